// Round 8
// baseline (161.775 us; speedup 1.0000x reference)
//
#include <hip/hip_runtime.h>
#include <hip/hip_bf16.h>

typedef __bf16 bf16x8 __attribute__((ext_vector_type(8)));
typedef float f32x4 __attribute__((ext_vector_type(4)));

#define N_NODES 50000
#define NEDGE 160000
#define NSLOT (2 * N_NODES)
#define CS2 100352           // 98 * 1024 padded combined-slot stride
#define BLKS 98
#define HSZ ((size_t)N_NODES * 128)

// ---- workspace layout (bytes) ----
constexpr size_t OFF_WFRAG = 0;                                    // 65536
constexpr size_t OFF_XB    = 65536;                                // 25.6 MB
constexpr size_t OFF_Y     = OFF_XB + 25600000;                    // 51.2 MB
constexpr size_t OFF_CNTA  = OFF_Y + 51200000;                     // CS2*4
constexpr size_t OFF_CNTB  = OFF_CNTA + (size_t)CS2 * 4;           // CS2*4 (contiguous w/ CNTA)
constexpr size_t OFF_IPTR  = OFF_CNTB + (size_t)CS2 * 4;
constexpr size_t OFF_CURA  = OFF_IPTR + (size_t)CS2 * 4;
constexpr size_t OFF_CURB  = OFF_CURA + (size_t)CS2 * 4;
constexpr size_t OFF_PART  = OFF_CURB + (size_t)CS2 * 4;           // 98*4, pad 1024
constexpr size_t OFF_SRC   = OFF_PART + 1024;                      // (4E+64)*2 uint16

// Basis fragments: offset = (((b*8+n)*4+kk)*64+lane)*8 + j
// element = weight[b][k][o], k = kk*32 + (lane>>4)*8 + j, o = n*16 + (lane&15)
__global__ __launch_bounds__(256) void wfrag_kernel(const float* __restrict__ weight,
                                                    __bf16* __restrict__ wfrag) {
    int tid = blockIdx.x * 256 + threadIdx.x;  // 32768 total
    int j    = tid & 7;
    int lane = (tid >> 3) & 63;
    int kk   = (tid >> 9) & 3;
    int n    = (tid >> 11) & 7;
    int b    = tid >> 14;
    int k = kk * 32 + ((lane >> 4) << 3) + j;
    int o = (n << 4) + (lane & 15);
    wfrag[tid] = (__bf16)weight[b * 16384 + k * 128 + o];
}

// xb[type*N + row] = bf16(x_type[row]), 8 floats -> 8 bf16 per thread
__global__ __launch_bounds__(256) void cast_kernel(const float* __restrict__ x0,
                                                   const float* __restrict__ x1,
                                                   __bf16* __restrict__ xb) {
    int ty = blockIdx.y;
    const float* x = ty ? x1 : x0;
    __bf16* o = xb + (size_t)ty * HSZ;
    int i = blockIdx.x * 256 + threadIdx.x;
    float4 f0 = reinterpret_cast<const float4*>(x)[2 * i];
    float4 f1 = reinterpret_cast<const float4*>(x)[2 * i + 1];
    union { __bf16 b[8]; uint4 v; } pk;
    pk.b[0] = (__bf16)f0.x; pk.b[1] = (__bf16)f0.y;
    pk.b[2] = (__bf16)f0.z; pk.b[3] = (__bf16)f0.w;
    pk.b[4] = (__bf16)f1.x; pk.b[5] = (__bf16)f1.y;
    pk.b[6] = (__bf16)f1.z; pk.b[7] = (__bf16)f1.w;
    reinterpret_cast<uint4*>(o)[i] = pk.v;
}

// countsA[slot] for type-0-src rels (0,1), countsB[slot] for type-1-src rels (2,3).
// slot = dst_ntype * N + dst. 4 independent atomic chains per thread.
__global__ __launch_bounds__(256) void hist_kernel(const int* __restrict__ d0,
                                                   const int* __restrict__ d1,
                                                   const int* __restrict__ d2,
                                                   const int* __restrict__ d3,
                                                   int* __restrict__ countsA,
                                                   int* __restrict__ countsB) {
    int tid = blockIdx.x * 256 + threadIdx.x;
    if (tid >= NEDGE) return;
    int v0 = d0[tid], v1 = d1[tid], v2 = d2[tid], v3 = d3[tid];
    atomicAdd(&countsA[v0], 1);
    atomicAdd(&countsA[N_NODES + v1], 1);
    atomicAdd(&countsB[v2], 1);
    atomicAdd(&countsB[N_NODES + v3], 1);
}

// Per-block partial sums of combined counts: 98 blocks x 1024 slots (int4/thread).
__global__ __launch_bounds__(256) void block_sums_kernel(const int* __restrict__ countsA,
                                                         const int* __restrict__ countsB,
                                                         int* __restrict__ partials) {
    int4 a = (reinterpret_cast<const int4*>(countsA) + blockIdx.x * 256)[threadIdx.x];
    int4 b = (reinterpret_cast<const int4*>(countsB) + blockIdx.x * 256)[threadIdx.x];
    int s = a.x + a.y + a.z + a.w + b.x + b.y + b.z + b.w;
#pragma unroll
    for (int d = 1; d < 64; d <<= 1) s += __shfl_xor(s, d, 64);
    __shared__ int wsum[4];
    int wave = threadIdx.x >> 6;
    int lane = threadIdx.x & 63;
    if (lane == 0) wsum[wave] = s;
    __syncthreads();
    if (threadIdx.x == 0)
        partials[blockIdx.x] = wsum[0] + wsum[1] + wsum[2] + wsum[3];
}

// Exclusive scan of combined counts -> indptr, cursorA = indptr, cursorB = indptr + cntA.
__global__ __launch_bounds__(256) void scan_write_kernel(const int* __restrict__ countsA,
                                                         const int* __restrict__ countsB,
                                                         const int* __restrict__ partials,
                                                         int* __restrict__ indptr,
                                                         int* __restrict__ cursorA,
                                                         int* __restrict__ cursorB) {
    int blk = blockIdx.x;
    int lane = threadIdx.x & 63;
    int wave = threadIdx.x >> 6;

    int pv = (lane < blk ? partials[lane] : 0) +
             (lane + 64 < blk ? partials[lane + 64] : 0);
#pragma unroll
    for (int d = 1; d < 64; d <<= 1) pv += __shfl_xor(pv, d, 64);

    int4 va = (reinterpret_cast<const int4*>(countsA) + blk * 256)[threadIdx.x];
    int4 vb = (reinterpret_cast<const int4*>(countsB) + blk * 256)[threadIdx.x];
    int4 v = {va.x + vb.x, va.y + vb.y, va.z + vb.z, va.w + vb.w};
    int ts = v.x + v.y + v.z + v.w;

    int s = ts;
#pragma unroll
    for (int d = 1; d < 64; d <<= 1) {
        int n = __shfl_up(s, d, 64);
        if (lane >= d) s += n;
    }
    int exclw = s - ts;

    __shared__ int wtot[4];
    if (lane == 63) wtot[wave] = s;
    __syncthreads();
    int woff = 0;
    if (wave > 0) woff += wtot[0];
    if (wave > 1) woff += wtot[1];
    if (wave > 2) woff += wtot[2];

    int e0 = pv + woff + exclw;
    int4 ip;
    ip.x = e0;
    ip.y = e0 + v.x;
    ip.z = ip.y + v.y;
    ip.w = ip.z + v.z;
    reinterpret_cast<int4*>(indptr)[blk * 256 + threadIdx.x] = ip;
    reinterpret_cast<int4*>(cursorA)[blk * 256 + threadIdx.x] = ip;
    int4 cb = {ip.x + va.x, ip.y + va.y, ip.z + va.z, ip.w + va.w};
    reinterpret_cast<int4*>(cursorB)[blk * 256 + threadIdx.x] = cb;
}

// srcids[pos] = (uint16) type-local src id. A-rels fill [ip, ip+cntA),
// B-rels fill [ip+cntA, ip+cnt). 4 independent chains per thread.
__global__ __launch_bounds__(256) void fill_kernel(const int* __restrict__ s0, const int* __restrict__ d0,
                                                   const int* __restrict__ s1, const int* __restrict__ d1,
                                                   const int* __restrict__ s2, const int* __restrict__ d2,
                                                   const int* __restrict__ s3, const int* __restrict__ d3,
                                                   int* __restrict__ cursorA,
                                                   int* __restrict__ cursorB,
                                                   unsigned short* __restrict__ srcids) {
    int tid = blockIdx.x * 256 + threadIdx.x;
    if (tid >= NEDGE) return;
    int p0 = atomicAdd(&cursorA[d0[tid]], 1);
    __builtin_nontemporal_store((unsigned short)s0[tid], &srcids[p0]);
    int p1 = atomicAdd(&cursorA[N_NODES + d1[tid]], 1);
    __builtin_nontemporal_store((unsigned short)s1[tid], &srcids[p1]);
    int p2 = atomicAdd(&cursorB[d2[tid]], 1);
    __builtin_nontemporal_store((unsigned short)s2[tid], &srcids[p2]);
    int p3 = atomicAdd(&cursorB[N_NODES + d3[tid]], 1);
    __builtin_nontemporal_store((unsigned short)s3[tid], &srcids[p3]);
}

// One wave per dst slot. Walk the A-segment and B-segment in the SAME unrolled
// iteration (4 A + 4 B independent gathers in flight). Coefficients at the end.
__global__ __launch_bounds__(256) void aggregate_y_kernel(const __bf16* __restrict__ xb,
                                                          const int* __restrict__ indptr,
                                                          const int* __restrict__ cntA,
                                                          const unsigned short* __restrict__ srcids,
                                                          const float* __restrict__ wcomp,
                                                          __bf16* __restrict__ y) {
    int idx = blockIdx.x * 256 + threadIdx.x;
    int slot = idx >> 6;
    int lane = idx & 63;
    int p = slot >= N_NODES;

    int beg = indptr[slot];
    int end = indptr[slot + 1];
    int dA  = cntA[slot];
    int dB  = end - beg - dA;
    const unsigned short* spA = srcids + beg;
    const unsigned short* spB = spA + dA;

    const unsigned int* x0u = reinterpret_cast<const unsigned int*>(xb);
    const unsigned int* x1u = x0u + (size_t)N_NODES * 64;

    int dAm1 = dA > 0 ? dA - 1 : 0;
    int dBm1 = dB > 0 ? dB - 1 : 0;
    int mx = dA > dB ? dA : dB;

    float aLo = 0.f, aHi = 0.f, bLo = 0.f, bHi = 0.f;

    for (int i = 0; i < mx; i += 4) {
        unsigned int hvA[4], hvB[4];
#pragma unroll
        for (int k = 0; k < 4; ++k) {
            int j = i + k;
            int jcA = j < dA ? j : dAm1;
            int jcB = j < dB ? j : dBm1;
            unsigned int sA = spA[jcA];
            unsigned int sB = spB[jcB];
            unsigned int vA = x0u[(size_t)sA * 64 + lane];
            unsigned int vB = x1u[(size_t)sB * 64 + lane];
            hvA[k] = j < dA ? vA : 0u;
            hvB[k] = j < dB ? vB : 0u;
        }
#pragma unroll
        for (int k = 0; k < 4; ++k) {
            union { unsigned int u; float f; } lo, hi;
            lo.u = hvA[k] << 16;  hi.u = hvA[k] & 0xFFFF0000u;
            aLo += lo.f;          aHi += hi.f;
            lo.u = hvB[k] << 16;  hi.u = hvB[k] & 0xFFFF0000u;
            bLo += lo.f;          bHi += hi.f;
        }
    }

    float cA0 = wcomp[p * 2],       cA1 = wcomp[p * 2 + 1];
    float cB0 = wcomp[(p + 2) * 2], cB1 = wcomp[(p + 2) * 2 + 1];
    float y0l = cA0 * aLo + cB0 * bLo;
    float y0h = cA0 * aHi + cB0 * bHi;
    float y1l = cA1 * aLo + cB1 * bLo;
    float y1h = cA1 * aHi + cB1 * bHi;

    union { __bf16 b[2]; unsigned int u; } p0, p1;
    p0.b[0] = (__bf16)y0l; p0.b[1] = (__bf16)y0h;
    p1.b[0] = (__bf16)y1l; p1.b[1] = (__bf16)y1h;
    unsigned int* yu = reinterpret_cast<unsigned int*>(y);
    yu[(size_t)slot * 128 + lane] = p0.u;        // basis 0 features
    yu[(size_t)slot * 128 + 64 + lane] = p1.u;   // basis 1 features
}

// out[slot] = y[slot][0]*B0 + y[slot][1]*B1 + bias. Operand-swapped MFMA
// (basis W^T as A) -> float4 stores. 64 slots/block, basis frags in LDS.
__global__ __launch_bounds__(256) void gemm_out_kernel(const __bf16* __restrict__ y,
                                                       const __bf16* __restrict__ wfrag,
                                                       const float* __restrict__ bias,
                                                       float* __restrict__ out) {
    __shared__ __bf16 wl[32768];  // 64 KB: both basis frag sets
    {
        const uint4* s = reinterpret_cast<const uint4*>(wfrag);
        uint4* dst = reinterpret_cast<uint4*>(wl);
        int t = threadIdx.x;
#pragma unroll
        for (int i = 0; i < 16; ++i) dst[t + i * 256] = s[t + i * 256];
    }
    __syncthreads();

    const int lane = threadIdx.x & 63;
    const int wave = threadIdx.x >> 6;
    const int g = lane >> 4;
    const int m15 = lane & 15;

    int node = blockIdx.x * 64 + wave * 16 + m15;
    int nodec = node < NSLOT ? node : NSLOT - 1;
    const __bf16* yr = y + (size_t)nodec * 256 + g * 8;

    bf16x8 yfrag[2][4];
#pragma unroll
    for (int b = 0; b < 2; ++b)
#pragma unroll
        for (int kk = 0; kk < 4; ++kk)
            yfrag[b][kk] = *reinterpret_cast<const bf16x8*>(yr + b * 128 + kk * 32);

    const bf16x8* wv = reinterpret_cast<const bf16x8*>(wl);
    bool valid = node < NSLOT;
    float* orow = out + (size_t)node * 128;

#pragma unroll
    for (int n = 0; n < 8; ++n) {
        float4 bv = *reinterpret_cast<const float4*>(bias + n * 16 + g * 4);
        f32x4 acc = (f32x4){bv.x, bv.y, bv.z, bv.w};
#pragma unroll
        for (int b = 0; b < 2; ++b)
#pragma unroll
            for (int kk = 0; kk < 4; ++kk)
                acc = __builtin_amdgcn_mfma_f32_16x16x32_bf16(
                    wv[((b * 8 + n) * 4 + kk) * 64 + lane], yfrag[b][kk], acc, 0, 0, 0);
        if (valid)
            *reinterpret_cast<float4*>(orow + n * 16 + g * 4) =
                (float4){acc[0], acc[1], acc[2], acc[3]};
    }
}

extern "C" void kernel_launch(void* const* d_in, const int* in_sizes, int n_in,
                              void* d_out, int out_size, void* d_ws, size_t ws_size,
                              hipStream_t stream) {
    const float* x0     = (const float*)d_in[0];
    const float* x1     = (const float*)d_in[1];
    const float* weight = (const float*)d_in[2];
    const float* wcomp  = (const float*)d_in[3];
    const float* bias   = (const float*)d_in[4];
    const int* src[4] = {(const int*)d_in[5], (const int*)d_in[7],
                         (const int*)d_in[9], (const int*)d_in[11]};
    const int* dst[4] = {(const int*)d_in[6], (const int*)d_in[8],
                         (const int*)d_in[10], (const int*)d_in[12]};
    float* out = (float*)d_out;

    char* ws = (char*)d_ws;
    __bf16* wfrag = (__bf16*)(ws + OFF_WFRAG);
    __bf16* xb    = (__bf16*)(ws + OFF_XB);
    __bf16* y     = (__bf16*)(ws + OFF_Y);
    int* countsA  = (int*)(ws + OFF_CNTA);
    int* countsB  = (int*)(ws + OFF_CNTB);
    int* indptr   = (int*)(ws + OFF_IPTR);
    int* cursorA  = (int*)(ws + OFF_CURA);
    int* cursorB  = (int*)(ws + OFF_CURB);
    int* partials = (int*)(ws + OFF_PART);
    unsigned short* srcids = (unsigned short*)(ws + OFF_SRC);

    wfrag_kernel<<<128, 256, 0, stream>>>(weight, wfrag);
    cast_kernel<<<dim3(3125, 2), 256, 0, stream>>>(x0, x1, xb);

    // ---- combined-slot CSR with per-type sub-segments ----
    hipMemsetAsync(countsA, 0, (size_t)2 * CS2 * 4, stream);  // A and B contiguous
    hist_kernel<<<(NEDGE + 255) / 256, 256, 0, stream>>>(
        dst[0], dst[1], dst[2], dst[3], countsA, countsB);
    block_sums_kernel<<<BLKS, 256, 0, stream>>>(countsA, countsB, partials);
    scan_write_kernel<<<BLKS, 256, 0, stream>>>(countsA, countsB, partials,
                                                indptr, cursorA, cursorB);
    fill_kernel<<<(NEDGE + 255) / 256, 256, 0, stream>>>(
        src[0], dst[0], src[1], dst[1], src[2], dst[2], src[3], dst[3],
        cursorA, cursorB, srcids);

    // ---- dual-segment interleaved gather-sum -> basis-combined y ----
    aggregate_y_kernel<<<NSLOT * 64 / 256, 256, 0, stream>>>(
        xb, indptr, countsA, srcids, wcomp, y);

    // ---- dense epilogue: out = y0*B0 + y1*B1 + bias ----
    gemm_out_kernel<<<(NSLOT + 63) / 64, 256, 0, stream>>>(y, wfrag, bias, out);
}